// Round 17
// baseline (68.059 us; speedup 1.0000x reference)
//
#include <hip/hip_runtime.h>

// ResNetVQC: 6 q3-layers of 32 three-qubit circuits + linear head.
// z_w = sum_p v0[p] * ( T[w][p][.] . m[.] ),  m = 9 monomials of (c1,s1,c2,s2),
// v0 = (1, c0, s0); evaluated with v_dot2_f32_f16 (T f16, f32 accumulate).
// T pre-scaled by 1/2pi (layers 0-4) so angles flow in REVOLUTIONS.
//
// Round-16: WAVE-AUTONOMOUS, ZERO barriers in the main loop.
//  * wave = 2 rows x 32 k (lane = 32*r + k): each lane evals ONE (row,k) per
//    layer. The "fully" permutation is within-row == within-wave -> exchange
//    via 9 ds_bpermute of packed (s,c) dwords + cndmask selects. No barrier.
//  * T per-lane from LDS, loaded once per block (stride 50 dwords per (l,k):
//    2-way bank aliasing = free; b64 reads, statically indexed into registers).
//    Zero scalar T loads, zero global T traffic in the loop.
//  * waves de-phase freely -> no lockstep resource pulses at layer boundaries.
//  * barriers: 1 after cooperative T load, 1 before classifier. That's all.

#define INV2PI 0.15915494309189535f
#define T_STRIDE 50   // dwords per (l,k) T block in LDS (48 + 2 pad)
#define T5_STRIDE 18  // dwords per k layer-5 block (16 + 2 pad)

typedef unsigned int u32;
typedef _Float16 hf2 __attribute__((ext_vector_type(2)));

#if __has_builtin(__builtin_amdgcn_fdot2)
#define HAVE_FDOT2 1
#else
#define HAVE_FDOT2 0
#endif

__device__ __forceinline__ float fdot2e(hf2 a, hf2 m, float acc) {
#if HAVE_FDOT2
  return __builtin_amdgcn_fdot2(a, m, acc, false);
#else
  return fmaf((float)a.x, (float)m.x, fmaf((float)a.y, (float)m.y, acc));
#endif
}

#if __has_builtin(__builtin_amdgcn_sinf)
__device__ __forceinline__ float hwsin(float r) { return __builtin_amdgcn_sinf(r); }
__device__ __forceinline__ float hwcos(float r) { return __builtin_amdgcn_cosf(r); }
#else
__device__ __forceinline__ float hwsin(float r) { return __sinf(r * 6.2831853071795865f); }
__device__ __forceinline__ float hwcos(float r) { return __cosf(r * 6.2831853071795865f); }
#endif

__device__ __forceinline__ hf2 pkrtz(float a, float b) {
#if __has_builtin(__builtin_amdgcn_cvt_pkrtz)
  return __builtin_bit_cast(hf2, __builtin_amdgcn_cvt_pkrtz(a, b));
#else
  hf2 v = {(_Float16)a, (_Float16)b};
  return v;
#endif
}

__device__ __forceinline__ u32 pk_sc(float hrev) {  // (sin|cos) packed dword
  return __builtin_bit_cast(u32, pkrtz(hwsin(hrev), hwcos(hrev)));
}
__device__ __forceinline__ hf2 as_hf2(u32 v) { return __builtin_bit_cast(hf2, v); }

// ---------------- setup kernel: build T (parallel: one block per (l,k)) -----
__global__ __launch_bounds__(64) void build_T(const float* __restrict__ thetas,
                                              hf2* __restrict__ Thp,
                                              hf2* __restrict__ T5) {
  const int l = blockIdx.x >> 5;
  const int k = blockIdx.x & 31;
  const int t = threadIdx.x;  // 0..63
  __shared__ float Ur[8][8], Ui[8][8];  // [col][amp]
  __shared__ float rem[3][8][8];
  __shared__ float tvs[3][27];

  // phase A: lanes 0-7 each build U column `t` (serial 54-gate circuit)
  if (t < 8) {
    const int col = t;
    float pr[8], pi[8];
#pragma unroll
    for (int j = 0; j < 8; ++j) { pr[j] = (j == col) ? 1.f : 0.f; pi[j] = 0.f; }
    const float* th = thetas + (size_t)(l * 32 + k) * 54;  // [d][w][3]
#pragma unroll
    for (int d = 0; d < 6; ++d) {
#pragma unroll
      for (int w = 0; w < 3; ++w) {
        float phi = th[(d * 3 + w) * 3 + 0];
        float tht = th[(d * 3 + w) * 3 + 1];
        float omg = th[(d * 3 + w) * 3 + 2];
        float st, ct, sp, cp, sm, cm;
        __sincosf(0.5f * tht, &st, &ct);
        __sincosf(0.5f * (phi + omg), &sp, &cp);
        __sincosf(0.5f * (phi - omg), &sm, &cm);
        float m00r =  cp * ct, m00i = -sp * ct;
        float m01r = -cm * st, m01i = -sm * st;
        float m10r =  cm * st, m10i = -sm * st;
        float m11r =  cp * ct, m11i =  sp * ct;
        const int s = 4 >> w;  // qubit0 = MSB
#pragma unroll
        for (int base = 0; base < 8; ++base) {
          if (base & s) continue;
          float ar = pr[base], ai = pi[base];
          float br = pr[base + s], bi = pi[base + s];
          pr[base]     = m00r * ar - m00i * ai + m01r * br - m01i * bi;
          pi[base]     = m00r * ai + m00i * ar + m01r * bi + m01i * br;
          pr[base + s] = m10r * ar - m10i * ai + m11r * br - m11i * bi;
          pi[base + s] = m10r * ai + m10i * ar + m11r * bi + m11i * br;
        }
      }
      const int r = (d & 1) + 1;  // CNOT ring: ranges 1,2,1,2,...
#pragma unroll
      for (int w = 0; w < 3; ++w) {
        const int cs = 4 >> w;
        const int ts = 4 >> ((w + r) % 3);
#pragma unroll
        for (int idx = 0; idx < 8; ++idx) {
          if (!(idx & cs) || (idx & ts)) continue;
          const int j2 = idx | ts;
          float tr = pr[idx]; pr[idx] = pr[j2]; pr[j2] = tr;
          float ti = pi[idx]; pi[idx] = pi[j2]; pi[j2] = ti;
        }
      }
    }
#pragma unroll
    for (int j = 0; j < 8; ++j) { Ur[col][j] = pr[j]; Ui[col][j] = pi[j]; }
  }
  __syncthreads();

  // phase B: 64 lanes: rem_w[a][b] = sum_c zs_w(c)*(U*[c,a]U[c,b]); U[c][a]=Ur[a][c]
  {
    const int a = t >> 3, bb = t & 7;
#pragma unroll
    for (int w = 0; w < 3; ++w) {
      float acc = 0.f;
#pragma unroll
      for (int c = 0; c < 8; ++c) {
        float zs = ((c >> (2 - w)) & 1) ? -1.f : 1.f;
        acc += zs * (Ur[a][c] * Ur[bb][c] + Ui[a][c] * Ui[bb][c]);
      }
      rem[w][a][bb] = acc;
    }
  }
  __syncthreads();

  // phase C: 81 tv entries (basis change to monomials)
  {
    const int   ga[3][2] = {{0, 1}, {0, 1}, {0, 1}};
    const int   gb[3][2] = {{0, 1}, {0, 1}, {1, 0}};
    const float gc[3][2] = {{0.5f, 0.5f}, {0.5f, -0.5f}, {0.5f, 0.5f}};
    const int MONO[3][3] = {{0, 3, 4}, {1, 5, 6}, {2, 7, 8}};
    for (int e = t; e < 81; e += 64) {
      int w = e / 27, re = e % 27;
      int p = re / 9, q = (re % 9) / 3, r = re % 3;
      float acc = 0.f;
#pragma unroll
      for (int e0 = 0; e0 < 2; ++e0)
#pragma unroll
        for (int e1 = 0; e1 < 2; ++e1)
#pragma unroll
          for (int e2 = 0; e2 < 2; ++e2) {
            int a  = (ga[p][e0] << 2) | (ga[q][e1] << 1) | ga[r][e2];
            int bb = (gb[p][e0] << 2) | (gb[q][e1] << 1) | gb[r][e2];
            acc += gc[p][e0] * gc[q][e1] * gc[r][e2] * rem[w][a][bb];
          }
      tvs[w][p * 9 + MONO[q][r]] = acc;
    }
  }
  __syncthreads();

  // phase D: pack to hf2 pairs. u = p*5+d: d<4 -> (2d,2d+1); d==4 -> (8, 0).
  if (l < 5) {
    if (t < 48) {
      int w = t >> 4, u = t & 15;
      hf2 v;
      if (u < 15) {
        int p = u / 5, d = u % 5;
        float lo = tvs[w][p * 9 + ((d == 4) ? 8 : 2 * d)] * INV2PI;
        float hi = (d == 4) ? 0.f : tvs[w][p * 9 + 2 * d + 1] * INV2PI;
        v = pkrtz(lo, hi);
      } else {
        v = pkrtz(0.f, 0.f);
      }
      Thp[((size_t)(l * 32 + k)) * 48 + w * 16 + u] = v;
    }
  } else {
    if (t < 16) {  // wire 0 only, unscaled
      int u = t;
      hf2 v;
      if (u < 15) {
        int p = u / 5, d = u % 5;
        float lo = tvs[0][p * 9 + ((d == 4) ? 8 : 2 * d)];
        float hi = (d == 4) ? 0.f : tvs[0][p * 9 + 2 * d + 1];
        v = pkrtz(lo, hi);
      } else {
        v = pkrtz(0.f, 0.f);
      }
      T5[k * 16 + u] = v;
    }
  }
}

// ---------------- main kernel evals ----------------
// T dword n (compile-time) out of register-resident uint2 chunks.
__device__ __forceinline__ hf2 td(const uint2* __restrict__ ch, int n) {
  u32 d = (n & 1) ? ch[n >> 1].y : ch[n >> 1].x;
  return as_hf2(d);
}

// eval, all 3 wires; T = ch[0..23] (48 dwords); inputs packed (s,c) dwords.
__device__ __forceinline__ void evalk_r(const uint2* __restrict__ ch,
                                        u32 cw, u32 aw, u32 bw,
                                        float* __restrict__ z) {
  hf2 C = as_hf2(cw), A = as_hf2(aw), B = as_hf2(bw);
  hf2 Blo = __builtin_shufflevector(B, B, 0, 0);
  hf2 Bhi = __builtin_shufflevector(B, B, 1, 1);
  hf2 Pa = A * Blo;  // {m8, m6}
  hf2 Pb = A * Bhi;  // {m7, m5}
  const hf2 ONE2 = {(_Float16)1.0f, (_Float16)1.0f};
  const hf2 ZERO2 = {(_Float16)0.0f, (_Float16)0.0f};
  hf2 M0 = __builtin_shufflevector(ONE2, A, 0, 3);   // {1, c1}
  hf2 M1 = __builtin_shufflevector(A, B, 0, 3);      // {s1, c2}
  hf2 M2 = __builtin_shufflevector(B, Pb, 0, 3);     // {s2, m5}
  hf2 M3 = __builtin_shufflevector(Pa, Pb, 1, 2);    // {m6, m7}
  hf2 M4 = __builtin_shufflevector(Pa, ZERO2, 0, 2); // {m8, 0}
  float s0 = (float)C.x, c0 = (float)C.y;
#pragma unroll
  for (int w = 0; w < 3; ++w) {
    const int bdw = 16 * w;
    float P[3];
#pragma unroll
    for (int p = 0; p < 3; ++p) {
      const int o = bdw + p * 5;
      float acc = fdot2e(td(ch, o + 0), M0, 0.0f);
      acc = fdot2e(td(ch, o + 1), M1, acc);
      acc = fdot2e(td(ch, o + 2), M2, acc);
      acc = fdot2e(td(ch, o + 3), M3, acc);
      acc = fdot2e(td(ch, o + 4), M4, acc);
      P[p] = acc;
    }
    z[w] = fmaf(s0, P[2], fmaf(c0, P[1], P[0]));
  }
}

// layer-5 eval (wire 0) from f32 angles (revolutions); T = c5[0..7] (15 dwords).
__device__ __forceinline__ float evalk1_r(const uint2* __restrict__ c5,
                                          float a0, float a1, float a2) {
  float s0 = hwsin(a0), c0 = hwcos(a0);
  float s1 = hwsin(a1), c1 = hwcos(a1);
  float s2 = hwsin(a2), c2 = hwcos(a2);
  hf2 M0 = pkrtz(1.0f, c1);
  hf2 M1 = pkrtz(s1, c2);
  hf2 M2 = pkrtz(s2, c1 * c2);
  hf2 M3 = pkrtz(c1 * s2, s1 * c2);
  hf2 M4 = pkrtz(s1 * s2, 0.f);
  float P[3];
#pragma unroll
  for (int p = 0; p < 3; ++p) {
    const int o = p * 5;
    float acc = fdot2e(td(c5, o + 0), M0, 0.0f);
    acc = fdot2e(td(c5, o + 1), M1, acc);
    acc = fdot2e(td(c5, o + 2), M2, acc);
    acc = fdot2e(td(c5, o + 3), M3, acc);
    acc = fdot2e(td(c5, o + 4), M4, acc);
    P[p] = acc;
  }
  return fmaf(s0, P[2], fmaf(c0, P[1], P[0]));
}

// 512 threads = 8 waves = 16 rows/block; lane = 32*r2 + k (r2 = row in wave,
// k = block index). One eval per lane per layer. Exchange via ds_bpermute
// within the wave (no barriers). T per-lane from LDS (loaded once per block).
__global__ __launch_bounds__(512, 4) void vqc_main(const float* __restrict__ x,
                                                   const hf2* __restrict__ Thp,
                                                   const hf2* __restrict__ T5,
                                                   const float* __restrict__ wcls,
                                                   const float* __restrict__ bcls,
                                                   float* __restrict__ out) {
  __shared__ u32 Tl[5 * 32 * T_STRIDE];   // 8000 dwords = 32000 B
  __shared__ u32 T5l[32 * T5_STRIDE];     // 576 dwords  =  2304 B
  __shared__ float zbuf[16 * 33];         // 528 floats  =  2112 B
  const int t = threadIdx.x;

  // cooperative T load (coalesced global reads; padded LDS writes)
  const u32* Tg = (const u32*)Thp;  // 7680 dwords, stride 48 per (l,k)
  for (int g = t; g < 7680; g += 512) {
    int lk = g / 48, c = g - lk * 48;
    Tl[lk * T_STRIDE + c] = Tg[g];
  }
  {
    const u32* T5g = (const u32*)T5;  // 512 dwords, stride 16 per k
    int k5 = t >> 4, c5 = t & 15;
    if (t < 512) T5l[k5 * T5_STRIDE + c5] = T5g[t];
  }

  const int lane = t & 63;
  const int wv = t >> 6;        // wave 0..7
  const int r2 = lane >> 5;     // row within wave 0/1
  const int k = lane & 31;      // block index
  const int row = (wv << 1) | r2;  // 0..15
  const size_t grow = (size_t)blockIdx.x * 16 + row;

  // stage own 3 angles -> packed (s,c), revolutions
  const float* xr = x + grow * 96 + 3 * k;
  u32 w0 = pk_sc(xr[0] * INV2PI);
  u32 w1 = pk_sc(xr[1] * INV2PI);
  u32 w2 = pk_sc(xr[2] * INV2PI);

  // exchange precompute: slot m = 3k+j -> src lane (r2<<5)|(m&31), wire m>>5
  int addrj[3], jp[3];
#pragma unroll
  for (int j = 0; j < 3; ++j) {
    int m = 3 * k + j;
    addrj[j] = (((r2 << 5) | (m & 31)) << 2);  // byte address for bpermute
    jp[j] = m >> 5;
  }

  __syncthreads();  // T ready; ONLY loop-external barrier

  float h[3];
#pragma unroll
  for (int l = 0; l < 5; ++l) {
    // T block -> registers (24 x ds_read_b64; stride-50 base -> 2-way = free)
    const u32* tb = &Tl[(l * 32 + k) * T_STRIDE];
    uint2 ch[24];
#pragma unroll
    for (int c2 = 0; c2 < 24; ++c2) ch[c2] = *(const uint2*)&tb[2 * c2];
    float z[3];
    evalk_r(ch, w0, w1, w2, z);
    if (l == 0) {
#pragma unroll
      for (int j = 0; j < 3; ++j) h[j] = z[j];
    } else {
#pragma unroll
      for (int j = 0; j < 3; ++j) h[j] += z[j];
    }
    if (l < 4) {
      // within-wave "fully" exchange: pack own wires, bpermute, select
      u32 p0 = pk_sc(h[0]), p1 = pk_sc(h[1]), p2 = pk_sc(h[2]);
      u32 nw[3];
#pragma unroll
      for (int j = 0; j < 3; ++j) {
        u32 v0 = __builtin_amdgcn_ds_bpermute(addrj[j], p0);
        u32 v1 = __builtin_amdgcn_ds_bpermute(addrj[j], p1);
        u32 v2 = __builtin_amdgcn_ds_bpermute(addrj[j], p2);
        nw[j] = (jp[j] == 0) ? v0 : ((jp[j] == 1) ? v1 : v2);
      }
      w0 = nw[0]; w1 = nw[1]; w2 = nw[2];
    }
  }

  // layer 5 (reduce, wire 0): inputs = own h (natural order)
  {
    const u32* t5b = &T5l[k * T5_STRIDE];
    uint2 c5[8];
#pragma unroll
    for (int c2 = 0; c2 < 8; ++c2) c5[c2] = *(const uint2*)&t5b[2 * c2];
    zbuf[row * 33 + k] = evalk1_r(c5, h[0], h[1], h[2]);
  }
  __syncthreads();

  // classifier: out[row][c] = sum_k z[row][k] * wcls[c][k] + bcls[c]
  if (t < 160) {
    int bb = t / 10, c = t - bb * 10;
    float acc = bcls[c];
#pragma unroll
    for (int k2 = 0; k2 < 32; ++k2)
      acc = fmaf(zbuf[bb * 33 + k2], wcls[c * 32 + k2], acc);
    out[((size_t)blockIdx.x * 16 + bb) * 10 + c] = acc;
  }
}

extern "C" void kernel_launch(void* const* d_in, const int* in_sizes, int n_in,
                              void* d_out, int out_size, void* d_ws, size_t ws_size,
                              hipStream_t stream) {
  const float* x  = (const float*)d_in[0];   // (65536, 96) f32
  const float* th = (const float*)d_in[1];   // (6,32,6,3,3) f32
  const float* wc = (const float*)d_in[2];   // (10,32) f32
  const float* bc = (const float*)d_in[3];   // (10,) f32
  float* out = (float*)d_out;                // (65536,10) f32
  hf2* Thp = (hf2*)d_ws;                     // 5*32*48 hf2 (30.7 KB), 1/2pi-scaled
  hf2* T5  = Thp + 5 * 32 * 48;              // 32*16 hf2 (2 KB), unscaled

  build_T<<<192, 64, 0, stream>>>(th, Thp, T5);
  vqc_main<<<65536 / 16, 512, 0, stream>>>(x, Thp, T5, wc, bc, out);
}

// Round 18
// 47.935 us; speedup vs baseline: 1.4198x; 1.4198x over previous
//
#include <hip/hip_runtime.h>

// ResNetVQC: 6 q3-layers of 32 three-qubit circuits + linear head.
// z_w = sum_p v0[p] * ( T[w][p][.] . m[.] ),  m = 9 monomials of (c1,s1,c2,s2),
// v0 = (1, c0, s0); evaluated with v_dot2_f32_f16 (T f16, f32 accumulate).
//
// Round-18: TRANS-PIPE DIET (probe: is the hidden throughput cap v_sin/v_cos?)
//  * mid-network sincos args are bounded: z = <Z> in [-1,1] (radians, T now
//    UNSCALED). (sin z, cos z) via 7-FMA Taylor (err <= 2e-4 on [-1,1]).
//  * residual h never materialized as an angle: track (sin h, cos h) in f32
//    and update via the addition identity (4 FMA). sin(h+z)=sh*cz+ch*sz etc.
//  * hw v_sin/v_cos remain ONLY for the unbounded input x (24/thread, was 144).
//  * exchange still carries packed (s,c) f16 pairs; evalk_sc unchanged (r14).
//  * layer-5 eval takes tracked (s,c) directly - zero trans in the loop.

#define INV2PI 0.15915494309189535f

typedef unsigned int u32;
typedef _Float16 hf2 __attribute__((ext_vector_type(2)));

#if __has_builtin(__builtin_amdgcn_fdot2)
#define HAVE_FDOT2 1
#else
#define HAVE_FDOT2 0
#endif

__device__ __forceinline__ float fdot2e(hf2 a, hf2 m, float acc) {
#if HAVE_FDOT2
  return __builtin_amdgcn_fdot2(a, m, acc, false);
#else
  return fmaf((float)a.x, (float)m.x, fmaf((float)a.y, (float)m.y, acc));
#endif
}

#if __has_builtin(__builtin_amdgcn_sinf)
__device__ __forceinline__ float hwsin(float r) { return __builtin_amdgcn_sinf(r); }
__device__ __forceinline__ float hwcos(float r) { return __builtin_amdgcn_cosf(r); }
#else
__device__ __forceinline__ float hwsin(float r) { return __sinf(r * 6.2831853071795865f); }
__device__ __forceinline__ float hwcos(float r) { return __cosf(r * 6.2831853071795865f); }
#endif

__device__ __forceinline__ hf2 pkrtz(float a, float b) {
#if __has_builtin(__builtin_amdgcn_cvt_pkrtz)
  return __builtin_bit_cast(hf2, __builtin_amdgcn_cvt_pkrtz(a, b));
#else
  hf2 v = {(_Float16)a, (_Float16)b};
  return v;
#endif
}

__device__ __forceinline__ u32 pk_sc(float hrev) {  // (sin|cos) packed dword
  return __builtin_bit_cast(u32, pkrtz(hwsin(hrev), hwcos(hrev)));
}
__device__ __forceinline__ u32 pk2(float s, float c) {
  return __builtin_bit_cast(u32, pkrtz(s, c));
}
__device__ __forceinline__ hf2 as_hf2(u32 v) { return __builtin_bit_cast(hf2, v); }

// Taylor sincos for |z| <= ~1.05 (radians): 7 FMA-class ops, err <= 2.3e-4.
__device__ __forceinline__ void sc_poly(float z, float& sz, float& cz) {
  float z2 = z * z;
  float u = fmaf(z2, 8.3333338e-3f, -1.6666667e-1f);
  sz = z * fmaf(z2, u, 1.0f);
  float a = fmaf(z2, -1.3888889e-3f, 4.1666668e-2f);
  cz = fmaf(z2, fmaf(z2, a, -0.5f), 1.0f);
}

// ---------------- setup kernel: build T (parallel: one block per (l,k)) -----
__global__ __launch_bounds__(64) void build_T(const float* __restrict__ thetas,
                                              hf2* __restrict__ Thp,
                                              hf2* __restrict__ T5) {
  const int l = blockIdx.x >> 5;
  const int k = blockIdx.x & 31;
  const int t = threadIdx.x;  // 0..63
  __shared__ float Ur[8][8], Ui[8][8];  // [col][amp]
  __shared__ float rem[3][8][8];
  __shared__ float tvs[3][27];

  // phase A: lanes 0-7 each build U column `t` (serial 54-gate circuit)
  if (t < 8) {
    const int col = t;
    float pr[8], pi[8];
#pragma unroll
    for (int j = 0; j < 8; ++j) { pr[j] = (j == col) ? 1.f : 0.f; pi[j] = 0.f; }
    const float* th = thetas + (size_t)(l * 32 + k) * 54;  // [d][w][3]
#pragma unroll
    for (int d = 0; d < 6; ++d) {
#pragma unroll
      for (int w = 0; w < 3; ++w) {
        float phi = th[(d * 3 + w) * 3 + 0];
        float tht = th[(d * 3 + w) * 3 + 1];
        float omg = th[(d * 3 + w) * 3 + 2];
        float st, ct, sp, cp, sm, cm;
        __sincosf(0.5f * tht, &st, &ct);
        __sincosf(0.5f * (phi + omg), &sp, &cp);
        __sincosf(0.5f * (phi - omg), &sm, &cm);
        float m00r =  cp * ct, m00i = -sp * ct;
        float m01r = -cm * st, m01i = -sm * st;
        float m10r =  cm * st, m10i = -sm * st;
        float m11r =  cp * ct, m11i =  sp * ct;
        const int s = 4 >> w;  // qubit0 = MSB
#pragma unroll
        for (int base = 0; base < 8; ++base) {
          if (base & s) continue;
          float ar = pr[base], ai = pi[base];
          float br = pr[base + s], bi = pi[base + s];
          pr[base]     = m00r * ar - m00i * ai + m01r * br - m01i * bi;
          pi[base]     = m00r * ai + m00i * ar + m01r * bi + m01i * br;
          pr[base + s] = m10r * ar - m10i * ai + m11r * br - m11i * bi;
          pi[base + s] = m10r * ai + m10i * ar + m11r * bi + m11i * br;
        }
      }
      const int r = (d & 1) + 1;  // CNOT ring: ranges 1,2,1,2,...
#pragma unroll
      for (int w = 0; w < 3; ++w) {
        const int cs = 4 >> w;
        const int ts = 4 >> ((w + r) % 3);
#pragma unroll
        for (int idx = 0; idx < 8; ++idx) {
          if (!(idx & cs) || (idx & ts)) continue;
          const int j2 = idx | ts;
          float tr = pr[idx]; pr[idx] = pr[j2]; pr[j2] = tr;
          float ti = pi[idx]; pi[idx] = pi[j2]; pi[j2] = ti;
        }
      }
    }
#pragma unroll
    for (int j = 0; j < 8; ++j) { Ur[col][j] = pr[j]; Ui[col][j] = pi[j]; }
  }
  __syncthreads();

  // phase B: 64 lanes: rem_w[a][b] = sum_c zs_w(c)*(U*[c,a]U[c,b]); U[c][a]=Ur[a][c]
  {
    const int a = t >> 3, bb = t & 7;
#pragma unroll
    for (int w = 0; w < 3; ++w) {
      float acc = 0.f;
#pragma unroll
      for (int c = 0; c < 8; ++c) {
        float zs = ((c >> (2 - w)) & 1) ? -1.f : 1.f;
        acc += zs * (Ur[a][c] * Ur[bb][c] + Ui[a][c] * Ui[bb][c]);
      }
      rem[w][a][bb] = acc;
    }
  }
  __syncthreads();

  // phase C: 81 tv entries (basis change to monomials)
  {
    const int   ga[3][2] = {{0, 1}, {0, 1}, {0, 1}};
    const int   gb[3][2] = {{0, 1}, {0, 1}, {1, 0}};
    const float gc[3][2] = {{0.5f, 0.5f}, {0.5f, -0.5f}, {0.5f, 0.5f}};
    const int MONO[3][3] = {{0, 3, 4}, {1, 5, 6}, {2, 7, 8}};
    for (int e = t; e < 81; e += 64) {
      int w = e / 27, re = e % 27;
      int p = re / 9, q = (re % 9) / 3, r = re % 3;
      float acc = 0.f;
#pragma unroll
      for (int e0 = 0; e0 < 2; ++e0)
#pragma unroll
        for (int e1 = 0; e1 < 2; ++e1)
#pragma unroll
          for (int e2 = 0; e2 < 2; ++e2) {
            int a  = (ga[p][e0] << 2) | (ga[q][e1] << 1) | ga[r][e2];
            int bb = (gb[p][e0] << 2) | (gb[q][e1] << 1) | gb[r][e2];
            acc += gc[p][e0] * gc[q][e1] * gc[r][e2] * rem[w][a][bb];
          }
      tvs[w][p * 9 + MONO[q][r]] = acc;
    }
  }
  __syncthreads();

  // phase D: pack to hf2 pairs (ALL layers unscaled / radians).
  // u = p*5+d: d<4 -> (2d,2d+1); d==4 -> (8, 0).
  if (l < 5) {
    if (t < 48) {
      int w = t >> 4, u = t & 15;
      hf2 v;
      if (u < 15) {
        int p = u / 5, d = u % 5;
        float lo = tvs[w][p * 9 + ((d == 4) ? 8 : 2 * d)];
        float hi = (d == 4) ? 0.f : tvs[w][p * 9 + 2 * d + 1];
        v = pkrtz(lo, hi);
      } else {
        v = pkrtz(0.f, 0.f);
      }
      Thp[((size_t)(l * 32 + k)) * 48 + w * 16 + u] = v;
    }
  } else {
    if (t < 16) {  // wire 0 only
      int u = t;
      hf2 v;
      if (u < 15) {
        int p = u / 5, d = u % 5;
        float lo = tvs[0][p * 9 + ((d == 4) ? 8 : 2 * d)];
        float hi = (d == 4) ? 0.f : tvs[0][p * 9 + 2 * d + 1];
        v = pkrtz(lo, hi);
      } else {
        v = pkrtz(0.f, 0.f);
      }
      T5[k * 16 + u] = v;
    }
  }
}

// ---------------- main kernel evals ----------------
// Lean eval: inputs are packed (s,c) dwords; M built with 2 pk_mul + 5 shuffles.
// C=(s0|c0), A=(s1|c1), B=(s2|c2). T pairs: (1,c1)(s1,c2)(s2,m5)(m6,m7)(m8,0).
__device__ __forceinline__ void evalk_sc(const hf2* __restrict__ tb,
                                         u32 cw, u32 aw, u32 bw,
                                         float* __restrict__ z) {
  hf2 C = as_hf2(cw), A = as_hf2(aw), B = as_hf2(bw);
  hf2 Blo = __builtin_shufflevector(B, B, 0, 0);
  hf2 Bhi = __builtin_shufflevector(B, B, 1, 1);
  hf2 Pa = A * Blo;  // {s1*s2, c1*s2} = {m8, m6}
  hf2 Pb = A * Bhi;  // {s1*c2, c1*c2} = {m7, m5}
  const hf2 ONE2 = {(_Float16)1.0f, (_Float16)1.0f};
  const hf2 ZERO2 = {(_Float16)0.0f, (_Float16)0.0f};
  hf2 M0 = __builtin_shufflevector(ONE2, A, 0, 3);   // {1, c1}
  hf2 M1 = __builtin_shufflevector(A, B, 0, 3);      // {s1, c2}
  hf2 M2 = __builtin_shufflevector(B, Pb, 0, 3);     // {s2, m5}
  hf2 M3 = __builtin_shufflevector(Pa, Pb, 1, 2);    // {m6, m7}
  hf2 M4 = __builtin_shufflevector(Pa, ZERO2, 0, 2); // {m8, 0}
  float s0 = (float)C.x, c0 = (float)C.y;
#pragma unroll
  for (int w = 0; w < 3; ++w) {
    const hf2* tw = tb + w * 16;
    float P[3];
#pragma unroll
    for (int p = 0; p < 3; ++p) {
      const hf2* tt = tw + p * 5;
      float acc = fdot2e(tt[0], M0, 0.0f);
      acc = fdot2e(tt[1], M1, acc);
      acc = fdot2e(tt[2], M2, acc);
      acc = fdot2e(tt[3], M3, acc);
      acc = fdot2e(tt[4], M4, acc);
      P[p] = acc;
    }
    z[w] = fmaf(s0, P[2], fmaf(c0, P[1], P[0]));
  }
}

// layer-5 eval (wire 0) from tracked (s,c) pairs; tb = 16 hf2. zero trans.
__device__ __forceinline__ float evalk1_sc(const hf2* __restrict__ tb,
                                           float s0, float c0, float s1,
                                           float c1, float s2, float c2) {
  hf2 M0 = pkrtz(1.0f, c1);
  hf2 M1 = pkrtz(s1, c2);
  hf2 M2 = pkrtz(s2, c1 * c2);
  hf2 M3 = pkrtz(c1 * s2, s1 * c2);
  hf2 M4 = pkrtz(s1 * s2, 0.f);
  float P[3];
#pragma unroll
  for (int p = 0; p < 3; ++p) {
    const hf2* tt = tb + p * 5;
    float acc = fdot2e(tt[0], M0, 0.0f);
    acc = fdot2e(tt[1], M1, acc);
    acc = fdot2e(tt[2], M2, acc);
    acc = fdot2e(tt[3], M3, acc);
    acc = fdot2e(tt[4], M4, acc);
    P[p] = acc;
  }
  return fmaf(s0, P[2], fmaf(c0, P[1], P[0]));
}

// 512 threads = 8 waves; lane b = batch row (64/block); wave ws owns k in
// {4ws..4ws+3}; T wave-uniform (s_load). Exchange ex[64][100] dwords holds
// packed (s,c) per value in CONSUMER-ORDER slots (S[m] = H[3*(m%32)+m/32]);
// residual state = tracked (sin h, cos h) in f32 regs. 2 barriers per layer.
__global__ __launch_bounds__(512, 8) void vqc_main(const float* __restrict__ x,
                                                   const hf2* __restrict__ Thp,
                                                   const hf2* __restrict__ T5,
                                                   const float* __restrict__ wcls,
                                                   const float* __restrict__ bcls,
                                                   float* __restrict__ out) {
  __shared__ u32 ex[64 * 100];  // 25600 B
  const int t = threadIdx.x;
  const int b = t & 63;
  const int ws = __builtin_amdgcn_readfirstlane(t >> 6);
  const size_t b0 = (size_t)blockIdx.x * 64;

  // stage: load x coalesced, hw sincos (x is unbounded), pack -> natural slots
  const float4* xv = (const float4*)(x + b0 * 96);
#pragma unroll
  for (int i = 0; i < 3; ++i) {
    int f = t + i * 512;  // float4 index in 64x96 tile
    float4 v = xv[f];
    int d = 4 * f, row = d / 96, col = d % 96;
    uint4 pv;
    pv.x = pk_sc(v.x * INV2PI);
    pv.y = pk_sc(v.y * INV2PI);
    pv.z = pk_sc(v.z * INV2PI);
    pv.w = pk_sc(v.w * INV2PI);
    *(uint4*)&ex[row * 100 + col] = pv;
  }
  __syncthreads();

  float hs[4][3], hc[4][3];  // tracked (sin h, cos h)
  const int rb = b * 100 + 12 * ws;

#pragma unroll
  for (int l = 0; l < 5; ++l) {
    uint4 r0 = *(const uint4*)&ex[rb + 0];
    uint4 r1 = *(const uint4*)&ex[rb + 4];
    uint4 r2 = *(const uint4*)&ex[rb + 8];
    __syncthreads();  // all reads done before anyone overwrites
    u32 wvv[12] = {r0.x, r0.y, r0.z, r0.w, r1.x, r1.y,
                   r1.z, r1.w, r2.x, r2.y, r2.z, r2.w};
    const hf2* tb = Thp + ((size_t)l * 32 + 4 * ws) * 48;
#pragma unroll
    for (int i = 0; i < 4; ++i) {
      float zt[3];
      evalk_sc(tb + i * 48, wvv[3 * i + 0], wvv[3 * i + 1], wvv[3 * i + 2], zt);
#pragma unroll
      for (int j = 0; j < 3; ++j) {
        float sz, cz;
        sc_poly(zt[j], sz, cz);  // |z| <= ~1: polynomial, no trans
        if (l == 0) {
          hs[i][j] = sz; hc[i][j] = cz;
        } else {
          float t1 = hc[i][j] * sz;
          float t2 = hs[i][j] * sz;
          float ns = fmaf(hs[i][j], cz, t1);
          float nc = fmaf(hc[i][j], cz, -t2);
          hs[i][j] = ns; hc[i][j] = nc;
        }
      }
    }
    if (l < 4) {
      // S[32j+4ws+i] = (sin h, cos h) of h[i][j] (already tracked; pack only)
#pragma unroll
      for (int j = 0; j < 3; ++j) {
        uint4 wv;
        wv.x = pk2(hs[0][j], hc[0][j]);
        wv.y = pk2(hs[1][j], hc[1][j]);
        wv.z = pk2(hs[2][j], hc[2][j]);
        wv.w = pk2(hs[3][j], hc[3][j]);
        *(uint4*)&ex[b * 100 + 32 * j + 4 * ws] = wv;
      }
      __syncthreads();  // writes visible before next layer's reads
    }
  }

  // layer 5 (reduce, wire 0): inputs = tracked (s,c); stash z (f32) at [b][k]
  {
    float4 zv;
    zv.x = evalk1_sc(T5 + (4 * ws + 0) * 16, hs[0][0], hc[0][0], hs[0][1],
                     hc[0][1], hs[0][2], hc[0][2]);
    zv.y = evalk1_sc(T5 + (4 * ws + 1) * 16, hs[1][0], hc[1][0], hs[1][1],
                     hc[1][1], hs[1][2], hc[1][2]);
    zv.z = evalk1_sc(T5 + (4 * ws + 2) * 16, hs[2][0], hc[2][0], hs[2][1],
                     hc[2][1], hs[2][2], hc[2][2]);
    zv.w = evalk1_sc(T5 + (4 * ws + 3) * 16, hs[3][0], hc[3][0], hs[3][1],
                     hc[3][1], hs[3][2], hc[3][2]);
    *(float4*)&ex[b * 100 + 4 * ws] = zv;  // safe: layer-4 reads done
  }
  __syncthreads();

  // classifier: out[b][c] = sum_k z[b][k] * wcls[c][k] + bcls[c]
  for (int idx = t; idx < 640; idx += 512) {
    int bb = idx / 10, c = idx % 10;
    float acc = bcls[c];
#pragma unroll
    for (int k = 0; k < 32; ++k)
      acc = fmaf(__uint_as_float(ex[bb * 100 + k]), wcls[c * 32 + k], acc);
    out[(b0 + bb) * 10 + c] = acc;
  }
}

extern "C" void kernel_launch(void* const* d_in, const int* in_sizes, int n_in,
                              void* d_out, int out_size, void* d_ws, size_t ws_size,
                              hipStream_t stream) {
  const float* x  = (const float*)d_in[0];   // (65536, 96) f32
  const float* th = (const float*)d_in[1];   // (6,32,6,3,3) f32
  const float* wc = (const float*)d_in[2];   // (10,32) f32
  const float* bc = (const float*)d_in[3];   // (10,) f32
  float* out = (float*)d_out;                // (65536,10) f32
  hf2* Thp = (hf2*)d_ws;                     // 5*32*48 hf2 (30.7 KB), radians
  hf2* T5  = Thp + 5 * 32 * 48;              // 32*16 hf2 (2 KB), radians

  build_T<<<192, 64, 0, stream>>>(th, Thp, T5);
  vqc_main<<<65536 / 64, 512, 0, stream>>>(x, Thp, T5, wc, bc, out);
}

// Round 19
// 47.560 us; speedup vs baseline: 1.4310x; 1.0079x over previous
//
#include <hip/hip_runtime.h>

// ResNetVQC: 6 q3-layers of 32 three-qubit circuits + linear head.
// z_w = sum_p v0[p] * ( T[w][p][.] . m[.] ),  m = 9 monomials of (c1,s1,c2,s2),
// v0 = (1, c0, s0); evaluated with v_dot2_f32_f16 (T f16, f32 accumulate).
//
// Round-19:
//  * build_T: hw v_sin/v_cos (revolutions) instead of OCML __sincosf in the
//    serial gate loop (162 calls x ~40 instrs -> x ~4). T error ~1e-5 << the
//    5e-4 f16 quantization already present. e2e shaves ~3-5us.
//  * vqc_main: layer loop ROLLED (#pragma unroll 1): hot body ~3.5KB instead
//    of ~17KB -> probes the I$-fetch-bound hypothesis for the 42us plateau.
//    l==0 branch removed via hs=0/hc=1 init (addition identity gives h=z).
//  * math identical to r18: poly sincos for bounded mid-layer args, tracked
//    (sin h, cos h) residual, packed (s,c) f16 exchange, dot2 eval.

#define INV2PI 0.15915494309189535f

typedef unsigned int u32;
typedef _Float16 hf2 __attribute__((ext_vector_type(2)));

#if __has_builtin(__builtin_amdgcn_fdot2)
#define HAVE_FDOT2 1
#else
#define HAVE_FDOT2 0
#endif

__device__ __forceinline__ float fdot2e(hf2 a, hf2 m, float acc) {
#if HAVE_FDOT2
  return __builtin_amdgcn_fdot2(a, m, acc, false);
#else
  return fmaf((float)a.x, (float)m.x, fmaf((float)a.y, (float)m.y, acc));
#endif
}

#if __has_builtin(__builtin_amdgcn_sinf)
__device__ __forceinline__ float hwsin(float r) { return __builtin_amdgcn_sinf(r); }
__device__ __forceinline__ float hwcos(float r) { return __builtin_amdgcn_cosf(r); }
#else
__device__ __forceinline__ float hwsin(float r) { return __sinf(r * 6.2831853071795865f); }
__device__ __forceinline__ float hwcos(float r) { return __cosf(r * 6.2831853071795865f); }
#endif

__device__ __forceinline__ hf2 pkrtz(float a, float b) {
#if __has_builtin(__builtin_amdgcn_cvt_pkrtz)
  return __builtin_bit_cast(hf2, __builtin_amdgcn_cvt_pkrtz(a, b));
#else
  hf2 v = {(_Float16)a, (_Float16)b};
  return v;
#endif
}

__device__ __forceinline__ u32 pk_sc(float hrev) {  // (sin|cos) packed dword
  return __builtin_bit_cast(u32, pkrtz(hwsin(hrev), hwcos(hrev)));
}
__device__ __forceinline__ u32 pk2(float s, float c) {
  return __builtin_bit_cast(u32, pkrtz(s, c));
}
__device__ __forceinline__ hf2 as_hf2(u32 v) { return __builtin_bit_cast(hf2, v); }

// hw sincos of a RADIAN angle (converts to revolutions inline, 1 mul + 2 trans)
__device__ __forceinline__ void hw_sc_rad(float rad, float& s, float& c) {
  float rev = rad * INV2PI;
  s = hwsin(rev);
  c = hwcos(rev);
}

// Taylor sincos for |z| <= ~1.05 (radians): 7 FMA-class ops, err <= 2.3e-4.
__device__ __forceinline__ void sc_poly(float z, float& sz, float& cz) {
  float z2 = z * z;
  float u = fmaf(z2, 8.3333338e-3f, -1.6666667e-1f);
  sz = z * fmaf(z2, u, 1.0f);
  float a = fmaf(z2, -1.3888889e-3f, 4.1666668e-2f);
  cz = fmaf(z2, fmaf(z2, a, -0.5f), 1.0f);
}

// ---------------- setup kernel: build T (parallel: one block per (l,k)) -----
__global__ __launch_bounds__(64) void build_T(const float* __restrict__ thetas,
                                              hf2* __restrict__ Thp,
                                              hf2* __restrict__ T5) {
  const int l = blockIdx.x >> 5;
  const int k = blockIdx.x & 31;
  const int t = threadIdx.x;  // 0..63
  __shared__ float Ur[8][8], Ui[8][8];  // [col][amp]
  __shared__ float rem[3][8][8];
  __shared__ float tvs[3][27];

  // phase A: lanes 0-7 each build U column `t` (serial 54-gate circuit)
  if (t < 8) {
    const int col = t;
    float pr[8], pi[8];
#pragma unroll
    for (int j = 0; j < 8; ++j) { pr[j] = (j == col) ? 1.f : 0.f; pi[j] = 0.f; }
    const float* th = thetas + (size_t)(l * 32 + k) * 54;  // [d][w][3]
#pragma unroll
    for (int d = 0; d < 6; ++d) {
#pragma unroll
      for (int w = 0; w < 3; ++w) {
        float phi = th[(d * 3 + w) * 3 + 0];
        float tht = th[(d * 3 + w) * 3 + 1];
        float omg = th[(d * 3 + w) * 3 + 2];
        float st, ct, sp, cp, sm, cm;
        hw_sc_rad(0.5f * tht, st, ct);          // hw sincos: err ~1e-5 <<
        hw_sc_rad(0.5f * (phi + omg), sp, cp);  // f16 T quantization (5e-4)
        hw_sc_rad(0.5f * (phi - omg), sm, cm);
        float m00r =  cp * ct, m00i = -sp * ct;
        float m01r = -cm * st, m01i = -sm * st;
        float m10r =  cm * st, m10i = -sm * st;
        float m11r =  cp * ct, m11i =  sp * ct;
        const int s = 4 >> w;  // qubit0 = MSB
#pragma unroll
        for (int base = 0; base < 8; ++base) {
          if (base & s) continue;
          float ar = pr[base], ai = pi[base];
          float br = pr[base + s], bi = pi[base + s];
          pr[base]     = m00r * ar - m00i * ai + m01r * br - m01i * bi;
          pi[base]     = m00r * ai + m00i * ar + m01r * bi + m01i * br;
          pr[base + s] = m10r * ar - m10i * ai + m11r * br - m11i * bi;
          pi[base + s] = m10r * ai + m10i * ar + m11r * bi + m11i * br;
        }
      }
      const int r = (d & 1) + 1;  // CNOT ring: ranges 1,2,1,2,...
#pragma unroll
      for (int w = 0; w < 3; ++w) {
        const int cs = 4 >> w;
        const int ts = 4 >> ((w + r) % 3);
#pragma unroll
        for (int idx = 0; idx < 8; ++idx) {
          if (!(idx & cs) || (idx & ts)) continue;
          const int j2 = idx | ts;
          float tr = pr[idx]; pr[idx] = pr[j2]; pr[j2] = tr;
          float ti = pi[idx]; pi[idx] = pi[j2]; pi[j2] = ti;
        }
      }
    }
#pragma unroll
    for (int j = 0; j < 8; ++j) { Ur[col][j] = pr[j]; Ui[col][j] = pi[j]; }
  }
  __syncthreads();

  // phase B: 64 lanes: rem_w[a][b] = sum_c zs_w(c)*(U*[c,a]U[c,b]); U[c][a]=Ur[a][c]
  {
    const int a = t >> 3, bb = t & 7;
#pragma unroll
    for (int w = 0; w < 3; ++w) {
      float acc = 0.f;
#pragma unroll
      for (int c = 0; c < 8; ++c) {
        float zs = ((c >> (2 - w)) & 1) ? -1.f : 1.f;
        acc += zs * (Ur[a][c] * Ur[bb][c] + Ui[a][c] * Ui[bb][c]);
      }
      rem[w][a][bb] = acc;
    }
  }
  __syncthreads();

  // phase C: 81 tv entries (basis change to monomials)
  {
    const int   ga[3][2] = {{0, 1}, {0, 1}, {0, 1}};
    const int   gb[3][2] = {{0, 1}, {0, 1}, {1, 0}};
    const float gc[3][2] = {{0.5f, 0.5f}, {0.5f, -0.5f}, {0.5f, 0.5f}};
    const int MONO[3][3] = {{0, 3, 4}, {1, 5, 6}, {2, 7, 8}};
    for (int e = t; e < 81; e += 64) {
      int w = e / 27, re = e % 27;
      int p = re / 9, q = (re % 9) / 3, r = re % 3;
      float acc = 0.f;
#pragma unroll
      for (int e0 = 0; e0 < 2; ++e0)
#pragma unroll
        for (int e1 = 0; e1 < 2; ++e1)
#pragma unroll
          for (int e2 = 0; e2 < 2; ++e2) {
            int a  = (ga[p][e0] << 2) | (ga[q][e1] << 1) | ga[r][e2];
            int bb = (gb[p][e0] << 2) | (gb[q][e1] << 1) | gb[r][e2];
            acc += gc[p][e0] * gc[q][e1] * gc[r][e2] * rem[w][a][bb];
          }
      tvs[w][p * 9 + MONO[q][r]] = acc;
    }
  }
  __syncthreads();

  // phase D: pack to hf2 pairs (radians). u = p*5+d: d<4 -> (2d,2d+1); d==4 -> (8,0).
  if (l < 5) {
    if (t < 48) {
      int w = t >> 4, u = t & 15;
      hf2 v;
      if (u < 15) {
        int p = u / 5, d = u % 5;
        float lo = tvs[w][p * 9 + ((d == 4) ? 8 : 2 * d)];
        float hi = (d == 4) ? 0.f : tvs[w][p * 9 + 2 * d + 1];
        v = pkrtz(lo, hi);
      } else {
        v = pkrtz(0.f, 0.f);
      }
      Thp[((size_t)(l * 32 + k)) * 48 + w * 16 + u] = v;
    }
  } else {
    if (t < 16) {  // wire 0 only
      int u = t;
      hf2 v;
      if (u < 15) {
        int p = u / 5, d = u % 5;
        float lo = tvs[0][p * 9 + ((d == 4) ? 8 : 2 * d)];
        float hi = (d == 4) ? 0.f : tvs[0][p * 9 + 2 * d + 1];
        v = pkrtz(lo, hi);
      } else {
        v = pkrtz(0.f, 0.f);
      }
      T5[k * 16 + u] = v;
    }
  }
}

// ---------------- main kernel evals ----------------
// Lean eval: inputs are packed (s,c) dwords; M built with 2 pk_mul + 5 shuffles.
// C=(s0|c0), A=(s1|c1), B=(s2|c2). T pairs: (1,c1)(s1,c2)(s2,m5)(m6,m7)(m8,0).
__device__ __forceinline__ void evalk_sc(const hf2* __restrict__ tb,
                                         u32 cw, u32 aw, u32 bw,
                                         float* __restrict__ z) {
  hf2 C = as_hf2(cw), A = as_hf2(aw), B = as_hf2(bw);
  hf2 Blo = __builtin_shufflevector(B, B, 0, 0);
  hf2 Bhi = __builtin_shufflevector(B, B, 1, 1);
  hf2 Pa = A * Blo;  // {s1*s2, c1*s2} = {m8, m6}
  hf2 Pb = A * Bhi;  // {s1*c2, c1*c2} = {m7, m5}
  const hf2 ONE2 = {(_Float16)1.0f, (_Float16)1.0f};
  const hf2 ZERO2 = {(_Float16)0.0f, (_Float16)0.0f};
  hf2 M0 = __builtin_shufflevector(ONE2, A, 0, 3);   // {1, c1}
  hf2 M1 = __builtin_shufflevector(A, B, 0, 3);      // {s1, c2}
  hf2 M2 = __builtin_shufflevector(B, Pb, 0, 3);     // {s2, m5}
  hf2 M3 = __builtin_shufflevector(Pa, Pb, 1, 2);    // {m6, m7}
  hf2 M4 = __builtin_shufflevector(Pa, ZERO2, 0, 2); // {m8, 0}
  float s0 = (float)C.x, c0 = (float)C.y;
#pragma unroll
  for (int w = 0; w < 3; ++w) {
    const hf2* tw = tb + w * 16;
    float P[3];
#pragma unroll
    for (int p = 0; p < 3; ++p) {
      const hf2* tt = tw + p * 5;
      float acc = fdot2e(tt[0], M0, 0.0f);
      acc = fdot2e(tt[1], M1, acc);
      acc = fdot2e(tt[2], M2, acc);
      acc = fdot2e(tt[3], M3, acc);
      acc = fdot2e(tt[4], M4, acc);
      P[p] = acc;
    }
    z[w] = fmaf(s0, P[2], fmaf(c0, P[1], P[0]));
  }
}

// layer-5 eval (wire 0) from tracked (s,c) pairs; tb = 16 hf2. zero trans.
__device__ __forceinline__ float evalk1_sc(const hf2* __restrict__ tb,
                                           float s0, float c0, float s1,
                                           float c1, float s2, float c2) {
  hf2 M0 = pkrtz(1.0f, c1);
  hf2 M1 = pkrtz(s1, c2);
  hf2 M2 = pkrtz(s2, c1 * c2);
  hf2 M3 = pkrtz(c1 * s2, s1 * c2);
  hf2 M4 = pkrtz(s1 * s2, 0.f);
  float P[3];
#pragma unroll
  for (int p = 0; p < 3; ++p) {
    const hf2* tt = tb + p * 5;
    float acc = fdot2e(tt[0], M0, 0.0f);
    acc = fdot2e(tt[1], M1, acc);
    acc = fdot2e(tt[2], M2, acc);
    acc = fdot2e(tt[3], M3, acc);
    acc = fdot2e(tt[4], M4, acc);
    P[p] = acc;
  }
  return fmaf(s0, P[2], fmaf(c0, P[1], P[0]));
}

// 512 threads = 8 waves; lane b = batch row (64/block); wave ws owns k in
// {4ws..4ws+3}; T wave-uniform (s_load). Exchange ex[64][100] dwords holds
// packed (s,c) per value in CONSUMER-ORDER slots (S[m] = H[3*(m%32)+m/32]);
// residual state = tracked (sin h, cos h) in f32 regs. 2 barriers per layer.
// Layer loop ROLLED: ~3.5KB hot body (I$ probe).
__global__ __launch_bounds__(512, 8) void vqc_main(const float* __restrict__ x,
                                                   const hf2* __restrict__ Thp,
                                                   const hf2* __restrict__ T5,
                                                   const float* __restrict__ wcls,
                                                   const float* __restrict__ bcls,
                                                   float* __restrict__ out) {
  __shared__ u32 ex[64 * 100];  // 25600 B
  const int t = threadIdx.x;
  const int b = t & 63;
  const int ws = __builtin_amdgcn_readfirstlane(t >> 6);
  const size_t b0 = (size_t)blockIdx.x * 64;

  // stage: load x coalesced, hw sincos (x is unbounded), pack -> natural slots
  const float4* xv = (const float4*)(x + b0 * 96);
#pragma unroll
  for (int i = 0; i < 3; ++i) {
    int f = t + i * 512;  // float4 index in 64x96 tile
    float4 v = xv[f];
    int d = 4 * f, row = d / 96, col = d % 96;
    uint4 pv;
    pv.x = pk_sc(v.x * INV2PI);
    pv.y = pk_sc(v.y * INV2PI);
    pv.z = pk_sc(v.z * INV2PI);
    pv.w = pk_sc(v.w * INV2PI);
    *(uint4*)&ex[row * 100 + col] = pv;
  }
  __syncthreads();

  float hs[4][3], hc[4][3];  // tracked (sin h, cos h); h starts at 0
#pragma unroll
  for (int i = 0; i < 4; ++i)
#pragma unroll
    for (int j = 0; j < 3; ++j) { hs[i][j] = 0.f; hc[i][j] = 1.f; }

  const int rb = b * 100 + 12 * ws;

#pragma unroll 1  // ROLLED: small hot body
  for (int l = 0; l < 5; ++l) {
    uint4 r0 = *(const uint4*)&ex[rb + 0];
    uint4 r1 = *(const uint4*)&ex[rb + 4];
    uint4 r2 = *(const uint4*)&ex[rb + 8];
    __syncthreads();  // all reads done before anyone overwrites
    u32 wvv[12] = {r0.x, r0.y, r0.z, r0.w, r1.x, r1.y,
                   r1.z, r1.w, r2.x, r2.y, r2.z, r2.w};
    const hf2* tb = Thp + ((size_t)l * 32 + 4 * ws) * 48;
#pragma unroll
    for (int i = 0; i < 4; ++i) {
      float zt[3];
      evalk_sc(tb + i * 48, wvv[3 * i + 0], wvv[3 * i + 1], wvv[3 * i + 2], zt);
#pragma unroll
      for (int j = 0; j < 3; ++j) {
        float sz, cz;
        sc_poly(zt[j], sz, cz);  // |z| <= ~1: polynomial, no trans
        // h += z via addition identity (h=0 init makes layer 0 exact)
        float t1 = hc[i][j] * sz;
        float t2 = hs[i][j] * sz;
        float ns = fmaf(hs[i][j], cz, t1);
        float nc = fmaf(hc[i][j], cz, -t2);
        hs[i][j] = ns; hc[i][j] = nc;
      }
    }
    if (l < 4) {
      // S[32j+4ws+i] = (sin h, cos h) of h[i][j] (already tracked; pack only)
#pragma unroll
      for (int j = 0; j < 3; ++j) {
        uint4 wv;
        wv.x = pk2(hs[0][j], hc[0][j]);
        wv.y = pk2(hs[1][j], hc[1][j]);
        wv.z = pk2(hs[2][j], hc[2][j]);
        wv.w = pk2(hs[3][j], hc[3][j]);
        *(uint4*)&ex[b * 100 + 32 * j + 4 * ws] = wv;
      }
      __syncthreads();  // writes visible before next layer's reads
    }
  }

  // layer 5 (reduce, wire 0): inputs = tracked (s,c); stash z (f32) at [b][k]
  {
    float4 zv;
    zv.x = evalk1_sc(T5 + (4 * ws + 0) * 16, hs[0][0], hc[0][0], hs[0][1],
                     hc[0][1], hs[0][2], hc[0][2]);
    zv.y = evalk1_sc(T5 + (4 * ws + 1) * 16, hs[1][0], hc[1][0], hs[1][1],
                     hc[1][1], hs[1][2], hc[1][2]);
    zv.z = evalk1_sc(T5 + (4 * ws + 2) * 16, hs[2][0], hc[2][0], hs[2][1],
                     hc[2][1], hs[2][2], hc[2][2]);
    zv.w = evalk1_sc(T5 + (4 * ws + 3) * 16, hs[3][0], hc[3][0], hs[3][1],
                     hc[3][1], hs[3][2], hc[3][2]);
    *(float4*)&ex[b * 100 + 4 * ws] = zv;  // safe: layer-4 reads done
  }
  __syncthreads();

  // classifier: out[b][c] = sum_k z[b][k] * wcls[c][k] + bcls[c]
  for (int idx = t; idx < 640; idx += 512) {
    int bb = idx / 10, c = idx % 10;
    float acc = bcls[c];
#pragma unroll
    for (int k = 0; k < 32; ++k)
      acc = fmaf(__uint_as_float(ex[bb * 100 + k]), wcls[c * 32 + k], acc);
    out[(b0 + bb) * 10 + c] = acc;
  }
}

extern "C" void kernel_launch(void* const* d_in, const int* in_sizes, int n_in,
                              void* d_out, int out_size, void* d_ws, size_t ws_size,
                              hipStream_t stream) {
  const float* x  = (const float*)d_in[0];   // (65536, 96) f32
  const float* th = (const float*)d_in[1];   // (6,32,6,3,3) f32
  const float* wc = (const float*)d_in[2];   // (10,32) f32
  const float* bc = (const float*)d_in[3];   // (10,) f32
  float* out = (float*)d_out;                // (65536,10) f32
  hf2* Thp = (hf2*)d_ws;                     // 5*32*48 hf2 (30.7 KB), radians
  hf2* T5  = Thp + 5 * 32 * 48;              // 32*16 hf2 (2 KB), radians

  build_T<<<192, 64, 0, stream>>>(th, Thp, T5);
  vqc_main<<<65536 / 64, 512, 0, stream>>>(x, Thp, T5, wc, bc, out);
}